// Round 1
// 140.070 us; speedup vs baseline: 1.0681x; 1.0681x over previous
//
#include <hip/hip_runtime.h>
#include <math.h>

// RUL loss: out = theta * sum(score(diff)) + (1-theta) * sqrt(mean(diff^2))
// score(d) = (d<0 ? exp(-d/13) : exp(d/10)) - 1
// N = 16777216 fp32. 134 MB logical read (~50% L3-resident after restore).
//
// R8 post-mortem: BLOCK_THREADS 256->512 invariant (43.x us). Kernel dur has
// been 42.4-45us across occupancy 40-70%, 2..16 loads/wave, block 256/512.
// No pipe saturated: HBM 19%, VALU 11%, 0 bank conflicts. Total read rate
// pinned at ~3.1 TB/s regardless of shape.
//
// R9 theory: the plateau is the L2 allocate/fill path, not the HBM interface.
// 134 MB streamed with zero reuse through 32 MB L2 = mandatory fill+evict per
// line; both HBM-miss and L3-hit traffic queue behind the same L2 fill port
// (~160-200 B/cy/XCD x 8 XCD ~= 3.1-3.9 TB/s). R6/R7 bundled nt with the
// fused-ticket regression and never isolated it. R9's single variable:
// __builtin_nontemporal_load on the two input streams (no-allocate streaming
// reads). Predict: partial-kernel dur 43 -> 25-33us if correct; invariant if
// the 3.1 TB/s is structural (-> ROOFLINE).

#define RUL_N 16777216
#define PART_BLOCKS 2048
#define BLOCK_THREADS 512
#define GRID_THREADS (PART_BLOCKS * BLOCK_THREADS)
#define ITERS ((RUL_N / 4) / GRID_THREADS)   // = 4, compile-time constant

typedef float f32x4 __attribute__((ext_vector_type(4)));

__global__ __launch_bounds__(BLOCK_THREADS) void rul_partial_kernel(
    const float* __restrict__ pred,
    const float* __restrict__ tru,
    float* __restrict__ partials /* [2 * PART_BLOCKS] */) {
    const f32x4* __restrict__ p4 = (const f32x4*)pred;
    const f32x4* __restrict__ t4 = (const f32x4*)tru;

    const int tid = blockIdx.x * BLOCK_THREADS + threadIdx.x;

    f32x4 p[ITERS];
    f32x4 t[ITERS];
#pragma unroll
    for (int k = 0; k < ITERS; ++k) {
        p[k] = __builtin_nontemporal_load(&p4[tid + k * GRID_THREADS]);
        t[k] = __builtin_nontemporal_load(&t4[tid + k * GRID_THREADS]);
    }

    float s_score0 = 0.0f, s_score1 = 0.0f;
    float s_sq0 = 0.0f, s_sq1 = 0.0f;
#pragma unroll
    for (int k = 0; k < ITERS; ++k) {
        float d0 = p[k][0] - t[k][0];
        float d1 = p[k][1] - t[k][1];
        float d2 = p[k][2] - t[k][2];
        float d3 = p[k][3] - t[k][3];

        float e0 = __expf(d0 * (d0 < 0.0f ? (-1.0f / 13.0f) : (1.0f / 10.0f)));
        float e1 = __expf(d1 * (d1 < 0.0f ? (-1.0f / 13.0f) : (1.0f / 10.0f)));
        float e2 = __expf(d2 * (d2 < 0.0f ? (-1.0f / 13.0f) : (1.0f / 10.0f)));
        float e3 = __expf(d3 * (d3 < 0.0f ? (-1.0f / 13.0f) : (1.0f / 10.0f)));

        s_score0 += (e0 - 1.0f) + (e1 - 1.0f);
        s_score1 += (e2 - 1.0f) + (e3 - 1.0f);
        s_sq0 += d0 * d0 + d1 * d1;
        s_sq1 += d2 * d2 + d3 * d3;
    }
    float s_score = s_score0 + s_score1;
    float s_sq = s_sq0 + s_sq1;

    // wave-64 reduce
#pragma unroll
    for (int off = 32; off > 0; off >>= 1) {
        s_score += __shfl_down(s_score, off);
        s_sq += __shfl_down(s_sq, off);
    }

    __shared__ float sm_score[BLOCK_THREADS / 64];
    __shared__ float sm_sq[BLOCK_THREADS / 64];
    const int wave = threadIdx.x >> 6;
    const int lane = threadIdx.x & 63;
    if (lane == 0) {
        sm_score[wave] = s_score;
        sm_sq[wave] = s_sq;
    }
    __syncthreads();
    if (threadIdx.x == 0) {
        float a = 0.0f, b = 0.0f;
#pragma unroll
        for (int w = 0; w < BLOCK_THREADS / 64; ++w) {
            a += sm_score[w];
            b += sm_sq[w];
        }
        partials[blockIdx.x] = a;
        partials[PART_BLOCKS + blockIdx.x] = b;
    }
}

#define FIN_THREADS 256

__global__ __launch_bounds__(FIN_THREADS) void rul_finalize_kernel(
    const float* __restrict__ partials,
    const float* __restrict__ theta_ptr,
    float* __restrict__ out) {
    float a = 0.0f, b = 0.0f;
#pragma unroll
    for (int i = threadIdx.x; i < PART_BLOCKS; i += FIN_THREADS) {
        a += partials[i];
        b += partials[PART_BLOCKS + i];
    }
#pragma unroll
    for (int off = 32; off > 0; off >>= 1) {
        a += __shfl_down(a, off);
        b += __shfl_down(b, off);
    }
    __shared__ float sm_a[FIN_THREADS / 64];
    __shared__ float sm_b[FIN_THREADS / 64];
    const int wave = threadIdx.x >> 6;
    const int lane = threadIdx.x & 63;
    if (lane == 0) {
        sm_a[wave] = a;
        sm_b[wave] = b;
    }
    __syncthreads();
    if (threadIdx.x == 0) {
        float sa = 0.0f, sb = 0.0f;
#pragma unroll
        for (int w = 0; w < FIN_THREADS / 64; ++w) {
            sa += sm_a[w];
            sb += sm_b[w];
        }
        float theta = theta_ptr[0];
        float rmse = sqrtf(sb * (1.0f / (float)RUL_N));
        out[0] = theta * sa + (1.0f - theta) * rmse;
    }
}

extern "C" void kernel_launch(void* const* d_in, const int* in_sizes, int n_in,
                              void* d_out, int out_size, void* d_ws, size_t ws_size,
                              hipStream_t stream) {
    const float* pred = (const float*)d_in[0];
    const float* tru = (const float*)d_in[1];
    const float* theta = (const float*)d_in[2];
    float* out = (float*)d_out;
    float* partials = (float*)d_ws; // 2 * PART_BLOCKS * 4 = 16 KB

    rul_partial_kernel<<<PART_BLOCKS, BLOCK_THREADS, 0, stream>>>(pred, tru, partials);
    rul_finalize_kernel<<<1, FIN_THREADS, 0, stream>>>(partials, theta, out);
}